// Round 5
// baseline (323.326 us; speedup 1.0000x reference)
//
#include <hip/hip_runtime.h>
#include <math.h>

#define BB_ 256
#define NN_ 512
#define SS_ 32
#define NP1 513
#define SP1 33
#define D_IN 1024
#define D_TYPE 259
#define INV_N (1.0f/512.0f)

typedef short s16x4 __attribute__((ext_vector_type(4)));
typedef short s16x8 __attribute__((ext_vector_type(8)));
typedef float f32x4 __attribute__((ext_vector_type(4)));

#if defined(__has_builtin)
#if __has_builtin(__builtin_amdgcn_rcpf)
#define FRCP(x) __builtin_amdgcn_rcpf(x)
#else
#define FRCP(x) (1.0f / (x))
#endif
#else
#define FRCP(x) (1.0f / (x))
#endif

__device__ __forceinline__ float fsig(float x) { return FRCP(1.0f + __expf(-x)); }
__device__ __forceinline__ float ftanh(float x) { return fmaf(-2.0f, FRCP(1.0f + __expf(2.0f * x)), 1.0f); }
__device__ __forceinline__ short f2bf(float f) {
    unsigned u = __float_as_uint(f);
    unsigned r = (u + 0x7FFFu + ((u >> 16) & 1u)) >> 16;
    return (short)r;
}
__device__ __forceinline__ float bf2f(short s) {
    unsigned u = ((unsigned)(unsigned short)s) << 16;
    return __uint_as_float(u);
}

// ---------------------------------------------------------------------------
// K1: pad_key(bf16)[b,n,:] = ENT x Wk^T via bf16 MFMA. grid 1024 x 256.
// 18 KB LDS -> 4+ blocks/CU; streams 134 MB ent at high occupancy.
// ---------------------------------------------------------------------------
__global__ __launch_bounds__(256) void key_kernel(
    const float* __restrict__ ent, const float* __restrict__ Wk,
    const float* __restrict__ bk, short* __restrict__ pkbf)
{
    __shared__ short a_lds[128 * 72];
    const int tid = threadIdx.x;
    const int lane = tid & 63, w = tid >> 6;
    const int nl = lane & 15, q = lane >> 4;
    const size_t rowbase = (size_t)blockIdx.x * 128;

    s16x8 bfr[8][2];
#pragma unroll
    for (int s = 0; s < 8; s++)
#pragma unroll
        for (int t = 0; t < 2; t++) {
            const float* src = Wk + (size_t)(t * 16 + nl) * 256 + s * 32 + q * 8;
            float4 v0 = *(const float4*)(src);
            float4 v1 = *(const float4*)(src + 4);
            s16x8 bv;
            bv[0] = f2bf(v0.x); bv[1] = f2bf(v0.y); bv[2] = f2bf(v0.z); bv[3] = f2bf(v0.w);
            bv[4] = f2bf(v1.x); bv[5] = f2bf(v1.y); bv[6] = f2bf(v1.z); bv[7] = f2bf(v1.w);
            bfr[s][t] = bv;
        }

    f32x4 acc[2][2];
#pragma unroll
    for (int mt = 0; mt < 2; mt++)
#pragma unroll
        for (int t = 0; t < 2; t++) acc[mt][t] = (f32x4)0.0f;

    for (int kc = 0; kc < 4; ++kc) {
        __syncthreads();
#pragma unroll
        for (int p = 0; p < 8; p++) {
            int flat = p * 256 + tid;
            int row = flat >> 4;
            int f4 = flat & 15;
            float4 v = *(const float4*)(ent + (rowbase + row) * 256 + kc * 64 + f4 * 4);
            s16x4 sv;
            sv[0] = f2bf(v.x); sv[1] = f2bf(v.y); sv[2] = f2bf(v.z); sv[3] = f2bf(v.w);
            *(s16x4*)&a_lds[row * 72 + f4 * 4] = sv;
        }
        __syncthreads();
#pragma unroll
        for (int ks = 0; ks < 2; ks++) {
            const int sg = kc * 2 + ks;
#pragma unroll
            for (int mt = 0; mt < 2; mt++) {
                s16x8 af = *(const s16x8*)&a_lds[(w * 32 + mt * 16 + nl) * 72 + ks * 32 + q * 8];
#pragma unroll
                for (int t = 0; t < 2; t++)
                    acc[mt][t] = __builtin_amdgcn_mfma_f32_16x16x32_bf16(af, bfr[sg][t], acc[mt][t], 0, 0, 0);
            }
        }
    }

    float bkv[2];
    bkv[0] = bk[nl]; bkv[1] = bk[16 + nl];
#pragma unroll
    for (int mt = 0; mt < 2; mt++)
#pragma unroll
        for (int t = 0; t < 2; t++)
#pragma unroll
            for (int r = 0; r < 4; r++) {
                int rowg = (int)rowbase + w * 32 + mt * 16 + q * 4 + r;
                int b = rowg >> 9, n = rowg & 511;
                pkbf[((size_t)b * NP1 + n) * 32 + t * 16 + nl] = f2bf(acc[mt][t][r] + bkv[t]);
            }
}

// ---------------------------------------------------------------------------
// K2 prep: blocks 0..32 comb; 33..288 actpre; 289 end-flag key rows.
// ---------------------------------------------------------------------------
__global__ __launch_bounds__(256) void prep_kernel(
    const float* __restrict__ Wemb, const float* __restrict__ bemb,
    const float* __restrict__ Wfc1, const float* __restrict__ emb0,
    const float* __restrict__ bfc1, const float* __restrict__ atm,
    const float* __restrict__ Wf, const float* __restrict__ bf,
    const float* __restrict__ endv,
    float* __restrict__ WcombT, float* __restrict__ cbv,
    float* __restrict__ act_pre, short* __restrict__ pkbf)
{
    __shared__ float col[D_IN];
    __shared__ float a_lds[16 * 260];
    __shared__ float w_lds[16 * 260];
    const int tid = threadIdx.x;

    if (blockIdx.x == 289) {
        short ev = 0;
        if (tid < 32) ev = f2bf(endv[tid]);
        const int k = tid & 31, b0 = tid >> 5;
        short evk = f2bf(endv[k]);
        for (int b = b0; b < BB_; b += 8)
            pkbf[((size_t)b * NP1 + 512) * 32 + k] = evk;
        (void)ev;
        return;
    }

    if (blockIdx.x < 33) {
        const int k = blockIdx.x;
        if (k < 32) {
            for (int p = 0; p < 4; p++) col[p * 256 + tid] = Wemb[(size_t)(p * 256 + tid) * 32 + k];
        } else {
            for (int p = 0; p < 4; p++) col[p * 256 + tid] = bemb[p * 256 + tid];
        }
        __syncthreads();
        const float* wr = Wfc1 + (size_t)tid * D_IN;
        float acc = 0.0f;
        for (int i4 = 0; i4 < 256; i4++) {
            float4 wv = *(const float4*)(wr + i4 * 4);
            acc = fmaf(col[i4*4+0], wv.x, acc);
            acc = fmaf(col[i4*4+1], wv.y, acc);
            acc = fmaf(col[i4*4+2], wv.z, acc);
            acc = fmaf(col[i4*4+3], wv.w, acc);
        }
        if (k < 32) WcombT[tid * 32 + k] = acc;
        else        cbv[tid] = acc;
    } else {
        const int idx = blockIdx.x - 33;
        const int jt = idx & 15, bt = idx >> 4;
        const int bb = tid >> 4, jj = tid & 15;

#pragma unroll 4
        for (int r = 0; r < 16; r++) {
            a_lds[r * 260 + tid] = atm[(size_t)(bt * 16 + r) * D_TYPE + tid];
            w_lds[r * 260 + tid] = Wf[(size_t)(jt * 16 + r) * D_TYPE + tid];
            if (tid < 3) {
                a_lds[r * 260 + 256 + tid] = atm[(size_t)(bt * 16 + r) * D_TYPE + 256 + tid];
                w_lds[r * 260 + 256 + tid] = Wf[(size_t)(jt * 16 + r) * D_TYPE + 256 + tid];
            }
        }
        __syncthreads();
        float accf = 0.0f;
        {
            const float4* ap = (const float4*)&a_lds[bb * 260];
            const float4* wp = (const float4*)&w_lds[jj * 260];
#pragma unroll 8
            for (int i4 = 0; i4 < 64; i4++) {
                float4 a = ap[i4]; float4 wv = wp[i4];
                accf = fmaf(a.x, wv.x, accf); accf = fmaf(a.y, wv.y, accf);
                accf = fmaf(a.z, wv.z, accf); accf = fmaf(a.w, wv.w, accf);
            }
            for (int i = 256; i < 259; i++) accf = fmaf(a_lds[bb * 260 + i], w_lds[jj * 260 + i], accf);
        }
        float acc = 0.0f;
        for (int c = 0; c < 4; c++) {
            __syncthreads();
#pragma unroll
            for (int p = 0; p < 4; p++) {
                int l4 = p * 256 + tid;
                int r = l4 >> 6, k4 = l4 & 63;
                *(float4*)&a_lds[r * 260 + k4 * 4] =
                    *(const float4*)(emb0 + (size_t)(bt * 16 + r) * D_IN + c * 256 + k4 * 4);
                *(float4*)&w_lds[r * 260 + k4 * 4] =
                    *(const float4*)(Wfc1 + (size_t)(jt * 16 + r) * D_IN + c * 256 + k4 * 4);
            }
            __syncthreads();
#pragma unroll 8
            for (int k4 = 0; k4 < 64; k4++) {
                float4 a = *(const float4*)&a_lds[bb * 260 + k4 * 4];
                float4 wv = *(const float4*)&w_lds[jj * 260 + k4 * 4];
                acc = fmaf(a.x, wv.x, acc); acc = fmaf(a.y, wv.y, acc);
                acc = fmaf(a.z, wv.z, acc); acc = fmaf(a.w, wv.w, acc);
            }
        }
        const int b = bt * 16 + bb, j = jt * 16 + jj;
        act_pre[b * 256 + j] = acc + bfc1[j] + fmaxf(accf + bf[j], 0.0f);
    }
}

// ---------------------------------------------------------------------------
// K3 scan: per-b recurrence. cumE gather (L2-hot pad_key), phase-split xg,
// LSTM chain, h -> bf16 global, emb_out. ~94 KB LDS, short-lived.
// ---------------------------------------------------------------------------
__global__ __launch_bounds__(256, 1) void scan_kernel(
    const short* __restrict__ pkbf, const float* __restrict__ act_pre0,
    const int* __restrict__ sel,
    const float* __restrict__ Wfc2, const float* __restrict__ bfc2,
    const float* __restrict__ Wih, const float* __restrict__ bih,
    const float* __restrict__ bhh, const float* __restrict__ Whh,
    const float* __restrict__ WcombT, const float* __restrict__ cbv,
    const float* __restrict__ emb0, const float* __restrict__ Wemb,
    const float* __restrict__ bemb,
    short* __restrict__ h_bf, float* __restrict__ emb_out)
{
    __shared__ float rap_l[SP1 * 260];
    __shared__ float red_l[SP1 * 256];
    __shared__ float xg_l[SP1 * 128];
    __shared__ float x_l[SP1 * 32];
    __shared__ float cumE_l[SP1 * 32];
    __shared__ float ssel_l[32];

    const int tid = threadIdx.x;
    const int b = blockIdx.x;

    // ---- P1: cumE prefix over selected keys ----
    {
        const int k = tid & 31, sq = tid >> 5;
        const int sq4 = sq * 4;
        int s0 = sel[b * SS_ + sq4 + 0];
        int s1 = sel[b * SS_ + sq4 + 1];
        int s2 = sel[b * SS_ + sq4 + 2];
        int s3 = sel[b * SS_ + sq4 + 3];
        float v0 = bf2f(pkbf[((size_t)b * NP1 + s0) * 32 + k]) * INV_N;
        float v1 = bf2f(pkbf[((size_t)b * NP1 + s1) * 32 + k]) * INV_N;
        float v2 = bf2f(pkbf[((size_t)b * NP1 + s2) * 32 + k]) * INV_N;
        float v3 = bf2f(pkbf[((size_t)b * NP1 + s3) * 32 + k]) * INV_N;
        float p0 = v0, p1 = p0 + v1, p2 = p1 + v2, p3 = p2 + v3;
        x_l[sq * 32 + k] = p3;
        __syncthreads();
        float off = 0.0f;
        for (int p = 0; p < 8; p++) if (p < sq) off += x_l[p * 32 + k];
        cumE_l[(sq4 + 1) * 32 + k] = off + p0;
        cumE_l[(sq4 + 2) * 32 + k] = off + p1;
        cumE_l[(sq4 + 3) * 32 + k] = off + p2;
        cumE_l[(sq4 + 4) * 32 + k] = off + p3;
        if (tid < 32) cumE_l[tid] = 0.0f;
        if (sq == 7) ssel_l[k] = off + p3;
    }
    __syncthreads();

    // ---- P2 Phase A: rap[t][j] ----
    {
        float wcr[32];
#pragma unroll
        for (int k4 = 0; k4 < 8; k4++) {
            float4 v = *(const float4*)(WcombT + (size_t)tid * 32 + k4 * 4);
            wcr[k4*4] = v.x; wcr[k4*4+1] = v.y; wcr[k4*4+2] = v.z; wcr[k4*4+3] = v.w;
        }
        const float cbr = cbv[tid];
        const float ap0v = act_pre0[b * 256 + tid];
        for (int t = 0; t < SP1; ++t) {
            float ap = fmaf((float)t, cbr, ap0v);
            const float4* ce = (const float4*)&cumE_l[t * 32];
#pragma unroll
            for (int k4 = 0; k4 < 8; k4++) {
                float4 e = ce[k4];
                ap = fmaf(e.x, wcr[k4*4], ap);   ap = fmaf(e.y, wcr[k4*4+1], ap);
                ap = fmaf(e.z, wcr[k4*4+2], ap); ap = fmaf(e.w, wcr[k4*4+3], ap);
            }
            rap_l[t * 260 + tid] = fmaxf(ap, 0.0f);
        }
    }
    __syncthreads();

    // ---- P2 Phase B: fc2 partials ----
    {
        const int seg = tid >> 5, i = tid & 31;
        float wfc2r[32];
#pragma unroll
        for (int i4 = 0; i4 < 8; i4++) {
            float4 v = *(const float4*)(Wfc2 + (size_t)i * 256 + seg * 32 + i4 * 4);
            wfc2r[i4*4] = v.x; wfc2r[i4*4+1] = v.y; wfc2r[i4*4+2] = v.z; wfc2r[i4*4+3] = v.w;
        }
        for (int t = 0; t < SP1; ++t) {
            float part = 0.0f;
            const float4* rp = (const float4*)&rap_l[t * 260 + seg * 32];
#pragma unroll
            for (int i4 = 0; i4 < 8; i4++) {
                float4 rv = rp[i4];
                part = fmaf(rv.x, wfc2r[i4*4], part);   part = fmaf(rv.y, wfc2r[i4*4+1], part);
                part = fmaf(rv.z, wfc2r[i4*4+2], part); part = fmaf(rv.w, wfc2r[i4*4+3], part);
            }
            red_l[t * 256 + seg * 32 + i] = part;
        }
    }
    __syncthreads();

    // ---- P2 Phase C: reduce -> x ----
    for (int p = 0; p < 5; p++) {
        int idx = p * 256 + tid;
        if (idx < SP1 * 32) {
            int t = idx >> 5, i = idx & 31;
            float x = bfc2[i];
#pragma unroll
            for (int s = 0; s < 8; s++) x += red_l[t * 256 + s * 32 + i];
            x_l[t * 32 + i] = x;
        }
    }
    __syncthreads();

    // ---- P2 Phase D: gates pre-h ----
    {
        const int g = tid & 127, half = tid >> 7;
        float wihr[32];
#pragma unroll
        for (int k4 = 0; k4 < 8; k4++) {
            float4 v = *(const float4*)(Wih + (size_t)g * 32 + k4 * 4);
            wihr[k4*4] = v.x; wihr[k4*4+1] = v.y; wihr[k4*4+2] = v.z; wihr[k4*4+3] = v.w;
        }
        const float bihg = bih[g] + bhh[g];
        for (int t = half; t < SP1; t += 2) {
            float gg = bihg;
            const float4* xp = (const float4*)&x_l[t * 32];
#pragma unroll
            for (int k4 = 0; k4 < 8; k4++) {
                float4 xv = xp[k4];
                gg = fmaf(xv.x, wihr[k4*4], gg);   gg = fmaf(xv.y, wihr[k4*4+1], gg);
                gg = fmaf(xv.z, wihr[k4*4+2], gg); gg = fmaf(xv.w, wihr[k4*4+3], gg);
            }
            xg_l[t * 128 + g] = gg;
        }
    }
    __syncthreads();

    // ---- P3: LSTM chain (wave 0) ----
    if (tid < 64) {
        float whh0[32], whh1[32];
#pragma unroll
        for (int k4 = 0; k4 < 8; k4++) {
            float4 v0 = *(const float4*)(Whh + (size_t)tid * 32 + k4 * 4);
            float4 v1 = *(const float4*)(Whh + (size_t)(tid + 64) * 32 + k4 * 4);
            whh0[k4*4] = v0.x; whh0[k4*4+1] = v0.y; whh0[k4*4+2] = v0.z; whh0[k4*4+3] = v0.w;
            whh1[k4*4] = v1.x; whh1[k4*4+1] = v1.y; whh1[k4*4+2] = v1.z; whh1[k4*4+3] = v1.w;
        }
        float c = 0.0f, h = 0.0f;
        for (int t = 0; t < SP1; ++t) {
            float g0 = xg_l[t * 128 + tid];
            float g1 = xg_l[t * 128 + 64 + tid];
            if (t > 0) {
#pragma unroll
                for (int k = 0; k < 32; k++) {
                    float hk = __shfl(h, k);
                    g0 = fmaf(hk, whh0[k], g0);
                    g1 = fmaf(hk, whh1[k], g1);
                }
            }
            float og0 = __shfl_xor(g0, 32);
            float og1 = __shfl_xor(g1, 32);
            float ig = fsig(g0);
            float fg = fsig(og0);
            float gv = ftanh(g1);
            float og = fsig(og1);
            float cn = fg * c + ig * gv;
            float hn = og * ftanh(cn);
            if (tid < 32) {
                c = cn; h = hn;
                h_bf[((size_t)b * SP1 + t) * 32 + tid] = f2bf(hn);
            }
        }
    }
    __syncthreads();

    // ---- P5: emb_out ----
#pragma unroll
    for (int p = 0; p < 4; p++) {
        int i = p * 256 + tid;
        float acc = emb0[(size_t)b * D_IN + i] + 32.0f * bemb[i];
        const float* wr = Wemb + (size_t)i * 32;
#pragma unroll
        for (int k4 = 0; k4 < 8; k4++) {
            float4 wv = *(const float4*)(wr + k4 * 4);
            acc = fmaf(ssel_l[k4*4+0], wv.x, acc);
            acc = fmaf(ssel_l[k4*4+1], wv.y, acc);
            acc = fmaf(ssel_l[k4*4+2], wv.z, acc);
            acc = fmaf(ssel_l[k4*4+3], wv.w, acc);
        }
        emb_out[(size_t)b * D_IN + i] = acc;
    }
}

// ---------------------------------------------------------------------------
// K4 logits: grid (256,4) x 256. bf16 fragments straight from global,
// 3 m-tiles x (2-3) n-tiles per wave, mask epilogue.
// ---------------------------------------------------------------------------
__global__ __launch_bounds__(256) void logits_kernel(
    const short* __restrict__ pkbf, const short* __restrict__ h_bf,
    const float* __restrict__ avail, const int* __restrict__ sel,
    float* __restrict__ logits)
{
    __shared__ float m0_l[144];
    __shared__ int   tf_l[144];
    __shared__ int   sel_l[SS_];
    const int tid = threadIdx.x;
    const int b = blockIdx.x, chunk = blockIdx.y;
    const int base_n = chunk * 128;
    const int cnt = (chunk == 3) ? 129 : 128;
    const int lane = tid & 63, w = tid >> 6;
    const int nl = lane & 15, q = lane >> 4;

    if (tid < SS_) sel_l[tid] = sel[b * SS_ + tid];
    if (tid < cnt) {
        int n = base_n + tid;
        m0_l[tid] = (n < NN_) ? avail[(size_t)b * NN_ + n] : 1.0f;
        tf_l[tid] = 1000;
    }
    __syncthreads();
    if (tid < cnt) {
        int n = base_n + tid;
        int tf = 1000; bool hit = false;
#pragma unroll 8
        for (int s = 0; s < SS_; s++) {
            if (sel_l[s] == n) { hit = true; if (s < tf) tf = s; }
        }
        if (hit) { m0_l[tid] = 1.0f; tf_l[tid] = tf; }
    }
    __syncthreads();

    s16x8 afr[3];
#pragma unroll
    for (int mt = 0; mt < 3; mt++) {
        int row = mt * 16 + nl;
        if (row < SP1) afr[mt] = *(const s16x8*)(h_bf + ((size_t)b * SP1 + row) * 32 + q * 8);
        else           afr[mt] = (s16x8)0;
    }

    const int ntiles = (cnt + 15) >> 4;   // 8 or 9
    for (int tt = w; tt < ntiles; tt += 4) {
        int n = base_n + tt * 16 + nl;
        bool nv = (tt * 16 + nl) < cnt;
        s16x8 bv = nv ? *(const s16x8*)(pkbf + ((size_t)b * NP1 + n) * 32 + q * 8) : (s16x8)0;
        f32x4 acc[3];
#pragma unroll
        for (int mt = 0; mt < 3; mt++)
            acc[mt] = __builtin_amdgcn_mfma_f32_16x16x32_bf16(afr[mt], bv, (f32x4)0.0f, 0, 0, 0);
        float m0v = nv ? m0_l[tt * 16 + nl] : 0.0f;
        int tfv = nv ? tf_l[tt * 16 + nl] : 0;
#pragma unroll
        for (int mt = 0; mt < 3; mt++)
#pragma unroll
            for (int r = 0; r < 4; r++) {
                int t = mt * 16 + q * 4 + r;
                if (t < SP1 && nv) {
                    float mv = (t <= tfv) ? m0v : 0.0f;
                    logits[((size_t)b * SP1 + t) * NP1 + n] = acc[mt][r] - (1.0f - mv) * 1e9f;
                }
            }
    }
}

extern "C" void kernel_launch(void* const* d_in, const int* in_sizes, int n_in,
                              void* d_out, int out_size, void* d_ws, size_t ws_size,
                              hipStream_t stream)
{
    (void)in_sizes; (void)n_in; (void)out_size; (void)ws_size;
    const float* embedding = (const float*)d_in[0];
    const float* atm       = (const float*)d_in[1];
    const float* avail     = (const float*)d_in[2];
    const float* ent       = (const float*)d_in[3];
    const int*   sel       = (const int*)  d_in[4];
    const float* endv      = (const float*)d_in[5];
    const float* Wk   = (const float*)d_in[6];
    const float* bk   = (const float*)d_in[7];
    const float* Wf   = (const float*)d_in[8];
    const float* bf   = (const float*)d_in[9];
    const float* Wfc1 = (const float*)d_in[10];
    const float* bfc1 = (const float*)d_in[11];
    const float* Wfc2 = (const float*)d_in[12];
    const float* bfc2 = (const float*)d_in[13];
    const float* Wemb = (const float*)d_in[14];
    const float* bemb = (const float*)d_in[15];
    const float* Wih  = (const float*)d_in[16];
    const float* bih  = (const float*)d_in[17];
    const float* Whh  = (const float*)d_in[18];
    const float* bhh  = (const float*)d_in[19];

    float* ws = (float*)d_ws;
    float* act_pre = ws;                          // 65536 f
    float* WcombT  = act_pre + BB_ * 256;         // 8192 f
    float* cbv     = WcombT + 256 * 32;           // 256 f
    short* pkbf    = (short*)(cbv + 256);         // 256*513*32 shorts
    short* h_bf    = pkbf + (size_t)BB_ * NP1 * 32; // 256*33*32 shorts

    float* logits  = (float*)d_out;
    float* emb_out = logits + (size_t)BB_ * SP1 * NP1;

    key_kernel<<<1024, 256, 0, stream>>>(ent, Wk, bk, pkbf);
    prep_kernel<<<290, 256, 0, stream>>>(Wemb, bemb, Wfc1, embedding, bfc1,
                                         atm, Wf, bf, endv, WcombT, cbv, act_pre, pkbf);
    scan_kernel<<<BB_, 256, 0, stream>>>(pkbf, act_pre, sel, Wfc2, bfc2,
                                         Wih, bih, bhh, Whh, WcombT, cbv,
                                         embedding, Wemb, bemb, h_bf, emb_out);
    logits_kernel<<<dim3(BB_, 4), 256, 0, stream>>>(pkbf, h_bf, avail, sel, logits);
}

// Round 6
// 312.257 us; speedup vs baseline: 1.0354x; 1.0354x over previous
//
#include <hip/hip_runtime.h>
#include <math.h>

#define BB_ 256
#define NN_ 512
#define SS_ 32
#define NP1 513
#define SP1 33
#define D_IN 1024
#define D_TYPE 259
#define INV_N (1.0f/512.0f)

typedef short s16x4 __attribute__((ext_vector_type(4)));
typedef short s16x8 __attribute__((ext_vector_type(8)));
typedef float f32x4 __attribute__((ext_vector_type(4)));

#if defined(__has_builtin)
#if __has_builtin(__builtin_amdgcn_rcpf)
#define FRCP(x) __builtin_amdgcn_rcpf(x)
#else
#define FRCP(x) (1.0f / (x))
#endif
#else
#define FRCP(x) (1.0f / (x))
#endif

__device__ __forceinline__ float fsig(float x) { return FRCP(1.0f + __expf(-x)); }
__device__ __forceinline__ float ftanh(float x) { return fmaf(-2.0f, FRCP(1.0f + __expf(2.0f * x)), 1.0f); }
__device__ __forceinline__ short f2bf(float f) {
    unsigned u = __float_as_uint(f);
    unsigned r = (u + 0x7FFFu + ((u >> 16) & 1u)) >> 16;
    return (short)r;
}
__device__ __forceinline__ float bf2f(short s) {
    unsigned u = ((unsigned)(unsigned short)s) << 16;
    return __uint_as_float(u);
}

// ---------------------------------------------------------------------------
// K1 fused front-end, grid 1283 x 256:
//   blocks 0..1023   : pad_key bf16 = ENT x Wk^T (MFMA), 128 rows each
//   blocks 1024..1025: WcombT/cbv = Wfc1 x [Wemb|bemb] (MFMA, LDS-staged B)
//   block  1026      : end-flag key rows
//   blocks 1027..1282: act_pre = emb0.Wfc1 + bfc1 + relu(atm.Wf + bf)
// ---------------------------------------------------------------------------
__global__ __launch_bounds__(256) void front_kernel(
    const float* __restrict__ ent, const float* __restrict__ Wk,
    const float* __restrict__ bk, const float* __restrict__ endv,
    const float* __restrict__ Wemb, const float* __restrict__ bemb,
    const float* __restrict__ Wfc1, const float* __restrict__ emb0,
    const float* __restrict__ bfc1, const float* __restrict__ atm,
    const float* __restrict__ Wf, const float* __restrict__ bf,
    short* __restrict__ pkbf, float* __restrict__ WcombT,
    float* __restrict__ cbv, float* __restrict__ act_pre)
{
    __shared__ char u_raw[33280];
    short* a_st   = (short*)u_raw;              // 128*72*2 = 18432 B
    float* wemb_s = (float*)(u_raw + 18688);    // 64*33*4  = 8448 B
    float* a_lds  = (float*)u_raw;              // actpre: 16*260*4
    float* w_lds  = (float*)(u_raw + 16640);

    const int tid = threadIdx.x;
    const int bid = blockIdx.x;
    const int lane = tid & 63, w = tid >> 6;
    const int nl = lane & 15, q = lane >> 4;

    if (bid < 1024) {
        // ================= key MFMA =================
        const size_t rowbase = (size_t)bid * 128;
        s16x8 bfr[8][2];
#pragma unroll
        for (int s = 0; s < 8; s++)
#pragma unroll
            for (int t = 0; t < 2; t++) {
                const float* src = Wk + (size_t)(t * 16 + nl) * 256 + s * 32 + q * 8;
                float4 v0 = *(const float4*)(src);
                float4 v1 = *(const float4*)(src + 4);
                s16x8 bv;
                bv[0] = f2bf(v0.x); bv[1] = f2bf(v0.y); bv[2] = f2bf(v0.z); bv[3] = f2bf(v0.w);
                bv[4] = f2bf(v1.x); bv[5] = f2bf(v1.y); bv[6] = f2bf(v1.z); bv[7] = f2bf(v1.w);
                bfr[s][t] = bv;
            }
        f32x4 acc[2][2];
#pragma unroll
        for (int mt = 0; mt < 2; mt++)
#pragma unroll
            for (int t = 0; t < 2; t++) acc[mt][t] = (f32x4)0.0f;

        for (int kc = 0; kc < 4; ++kc) {
            __syncthreads();
#pragma unroll
            for (int p = 0; p < 8; p++) {
                int flat = p * 256 + tid;
                int row = flat >> 4;
                int f4 = flat & 15;
                float4 v = *(const float4*)(ent + (rowbase + row) * 256 + kc * 64 + f4 * 4);
                s16x4 sv;
                sv[0] = f2bf(v.x); sv[1] = f2bf(v.y); sv[2] = f2bf(v.z); sv[3] = f2bf(v.w);
                *(s16x4*)&a_st[row * 72 + f4 * 4] = sv;
            }
            __syncthreads();
#pragma unroll
            for (int ks = 0; ks < 2; ks++) {
                const int sg = kc * 2 + ks;
#pragma unroll
                for (int mt = 0; mt < 2; mt++) {
                    s16x8 af = *(const s16x8*)&a_st[(w * 32 + mt * 16 + nl) * 72 + ks * 32 + q * 8];
#pragma unroll
                    for (int t = 0; t < 2; t++)
                        acc[mt][t] = __builtin_amdgcn_mfma_f32_16x16x32_bf16(af, bfr[sg][t], acc[mt][t], 0, 0, 0);
                }
            }
        }
        float bkv[2];
        bkv[0] = bk[nl]; bkv[1] = bk[16 + nl];
#pragma unroll
        for (int mt = 0; mt < 2; mt++)
#pragma unroll
            for (int t = 0; t < 2; t++)
#pragma unroll
                for (int r = 0; r < 4; r++) {
                    int rowg = (int)rowbase + w * 32 + mt * 16 + q * 4 + r;
                    int b = rowg >> 9, n = rowg & 511;
                    pkbf[((size_t)b * NP1 + n) * 32 + t * 16 + nl] = f2bf(acc[mt][t][r] + bkv[t]);
                }
    } else if (bid < 1026) {
        // ================= comb MFMA: WcombT[j][k], cbv[j] =================
        const int m0 = bid - 1024;     // 128-row group of j
        f32x4 acc[2][3];
#pragma unroll
        for (int mt = 0; mt < 2; mt++)
#pragma unroll
            for (int t = 0; t < 3; t++) acc[mt][t] = (f32x4)0.0f;

        for (int kc = 0; kc < 16; ++kc) {
            __syncthreads();
            // stage A: Wfc1 rows [m0*128,+128), cols [kc*64,+64) as bf16
#pragma unroll
            for (int p = 0; p < 8; p++) {
                int flat = p * 256 + tid;
                int row = flat >> 4;
                int f4 = flat & 15;
                float4 v = *(const float4*)(Wfc1 + (size_t)(m0 * 128 + row) * D_IN + kc * 64 + f4 * 4);
                s16x4 sv;
                sv[0] = f2bf(v.x); sv[1] = f2bf(v.y); sv[2] = f2bf(v.z); sv[3] = f2bf(v.w);
                *(s16x4*)&a_st[row * 72 + f4 * 4] = sv;
            }
            // stage B chunk: wemb_s[i_local][n] for i_local 0..63, n 0..32
            {
                int r = tid >> 2, c0 = tid & 3;
#pragma unroll
                for (int cc = 0; cc < 9; cc++) {
                    int col = c0 + cc * 4;
                    if (col < 33) {
                        float v = (col < 32) ? Wemb[(size_t)(kc * 64 + r) * 32 + col]
                                             : bemb[kc * 64 + r];
                        wemb_s[r * 33 + col] = v;
                    }
                }
            }
            __syncthreads();
#pragma unroll
            for (int ks = 0; ks < 2; ks++) {
                s16x8 bv[3];
#pragma unroll
                for (int t = 0; t < 3; t++) {
                    int n = t * 16 + nl;
#pragma unroll
                    for (int jj = 0; jj < 8; jj++) {
                        float v = (n < 33) ? wemb_s[(ks * 32 + q * 8 + jj) * 33 + n] : 0.0f;
                        bv[t][jj] = f2bf(v);
                    }
                }
#pragma unroll
                for (int mt = 0; mt < 2; mt++) {
                    s16x8 af = *(const s16x8*)&a_st[(w * 32 + mt * 16 + nl) * 72 + ks * 32 + q * 8];
#pragma unroll
                    for (int t = 0; t < 3; t++)
                        acc[mt][t] = __builtin_amdgcn_mfma_f32_16x16x32_bf16(af, bv[t], acc[mt][t], 0, 0, 0);
                }
            }
        }
#pragma unroll
        for (int mt = 0; mt < 2; mt++)
#pragma unroll
            for (int t = 0; t < 3; t++)
#pragma unroll
                for (int r = 0; r < 4; r++) {
                    int j = m0 * 128 + w * 32 + mt * 16 + q * 4 + r;
                    int n = t * 16 + nl;
                    if (n < 32) WcombT[j * 32 + n] = acc[mt][t][r];
                    else if (n == 32) cbv[j] = acc[mt][t][r];
                }
    } else if (bid == 1026) {
        // ================= end-flag key rows =================
        const int k = tid & 31, b0 = tid >> 5;
        short evk = f2bf(endv[k]);
        for (int b = b0; b < BB_; b += 8)
            pkbf[((size_t)b * NP1 + 512) * 32 + k] = evk;
    } else {
        // ================= actpre =================
        const int idx = bid - 1027;
        const int jt = idx & 15, bt = idx >> 4;
        const int bb = tid >> 4, jj = tid & 15;

#pragma unroll 4
        for (int r = 0; r < 16; r++) {
            a_lds[r * 260 + tid] = atm[(size_t)(bt * 16 + r) * D_TYPE + tid];
            w_lds[r * 260 + tid] = Wf[(size_t)(jt * 16 + r) * D_TYPE + tid];
            if (tid < 3) {
                a_lds[r * 260 + 256 + tid] = atm[(size_t)(bt * 16 + r) * D_TYPE + 256 + tid];
                w_lds[r * 260 + 256 + tid] = Wf[(size_t)(jt * 16 + r) * D_TYPE + 256 + tid];
            }
        }
        __syncthreads();
        float accf = 0.0f;
        {
            const float4* ap = (const float4*)&a_lds[bb * 260];
            const float4* wp = (const float4*)&w_lds[jj * 260];
#pragma unroll 8
            for (int i4 = 0; i4 < 64; i4++) {
                float4 a = ap[i4]; float4 wv = wp[i4];
                accf = fmaf(a.x, wv.x, accf); accf = fmaf(a.y, wv.y, accf);
                accf = fmaf(a.z, wv.z, accf); accf = fmaf(a.w, wv.w, accf);
            }
            for (int i = 256; i < 259; i++) accf = fmaf(a_lds[bb * 260 + i], w_lds[jj * 260 + i], accf);
        }
        float acc = 0.0f;
        for (int c = 0; c < 4; c++) {
            __syncthreads();
#pragma unroll
            for (int p = 0; p < 4; p++) {
                int l4 = p * 256 + tid;
                int r = l4 >> 6, k4 = l4 & 63;
                *(float4*)&a_lds[r * 260 + k4 * 4] =
                    *(const float4*)(emb0 + (size_t)(bt * 16 + r) * D_IN + c * 256 + k4 * 4);
                *(float4*)&w_lds[r * 260 + k4 * 4] =
                    *(const float4*)(Wfc1 + (size_t)(jt * 16 + r) * D_IN + c * 256 + k4 * 4);
            }
            __syncthreads();
#pragma unroll 8
            for (int k4 = 0; k4 < 64; k4++) {
                float4 a = *(const float4*)&a_lds[bb * 260 + k4 * 4];
                float4 wv = *(const float4*)&w_lds[jj * 260 + k4 * 4];
                acc = fmaf(a.x, wv.x, acc); acc = fmaf(a.y, wv.y, acc);
                acc = fmaf(a.z, wv.z, acc); acc = fmaf(a.w, wv.w, acc);
            }
        }
        const int b = bt * 16 + bb, j = jt * 16 + jj;
        act_pre[b * 256 + j] = acc + bfc1[j] + fmaxf(accf + bf[j], 0.0f);
    }
}

// ---------------------------------------------------------------------------
// K2 back-end, grid 256 x 256: scan recurrence + logits MFMA + emb_out,
// all per-b, h kept in LDS (no global round-trip). ~77 KB LDS, phase-overlaid.
// ---------------------------------------------------------------------------
__global__ __launch_bounds__(256, 1) void back_kernel(
    const short* __restrict__ pkbf, const float* __restrict__ act_pre0,
    const int* __restrict__ sel, const float* __restrict__ avail,
    const float* __restrict__ Wfc2, const float* __restrict__ bfc2,
    const float* __restrict__ Wih, const float* __restrict__ bih,
    const float* __restrict__ bhh, const float* __restrict__ Whh,
    const float* __restrict__ WcombT, const float* __restrict__ cbv,
    const float* __restrict__ emb0, const float* __restrict__ Wemb,
    const float* __restrict__ bemb,
    float* __restrict__ logits, float* __restrict__ emb_out)
{
    __shared__ float S[19204];
    __shared__ int sel_l[SS_];
    float* rap_l  = S;                    // 8580 (33*260)           [phase A-B]
    float* red_l  = S + 8580;             // 8448 (33*256)           [phase B-C]
    float* x_l    = S + 17028;            // 1056                    [P1 scratch, C-D]
    float* cumE_l = S + 18084;            // 1056
    float* ssel_l = S + 19140;            // 32
    float* xg_l   = S;                    // 4224, overlays rap (dead post-B)
    float* h_all  = S + 4224;             // 1056, overlays rap tail
    float* m0_l   = S + 8580;             // 513, overlays red (dead post-C)
    int*   tf_l   = (int*)(S + 9093);     // 513

    const int tid = threadIdx.x;
    const int b = blockIdx.x;
    const int lane = tid & 63, w = tid >> 6;
    const int nl = lane & 15, q = lane >> 4;

    if (tid < SS_) sel_l[tid] = sel[b * SS_ + tid];

    // ---- P1: cumE prefix over selected keys ----
    {
        const int k = tid & 31, sq = tid >> 5;
        const int sq4 = sq * 4;
        int s0 = sel[b * SS_ + sq4 + 0];
        int s1 = sel[b * SS_ + sq4 + 1];
        int s2 = sel[b * SS_ + sq4 + 2];
        int s3 = sel[b * SS_ + sq4 + 3];
        float v0 = bf2f(pkbf[((size_t)b * NP1 + s0) * 32 + k]) * INV_N;
        float v1 = bf2f(pkbf[((size_t)b * NP1 + s1) * 32 + k]) * INV_N;
        float v2 = bf2f(pkbf[((size_t)b * NP1 + s2) * 32 + k]) * INV_N;
        float v3 = bf2f(pkbf[((size_t)b * NP1 + s3) * 32 + k]) * INV_N;
        float p0 = v0, p1 = p0 + v1, p2 = p1 + v2, p3 = p2 + v3;
        x_l[sq * 32 + k] = p3;
        __syncthreads();
        float off = 0.0f;
        for (int p = 0; p < 8; p++) if (p < sq) off += x_l[p * 32 + k];
        cumE_l[(sq4 + 1) * 32 + k] = off + p0;
        cumE_l[(sq4 + 2) * 32 + k] = off + p1;
        cumE_l[(sq4 + 3) * 32 + k] = off + p2;
        cumE_l[(sq4 + 4) * 32 + k] = off + p3;
        if (tid < 32) cumE_l[tid] = 0.0f;
        if (sq == 7) ssel_l[k] = off + p3;
    }
    __syncthreads();

    // ---- Phase A: rap[t][j] ----
    {
        float wcr[32];
#pragma unroll
        for (int k4 = 0; k4 < 8; k4++) {
            float4 v = *(const float4*)(WcombT + (size_t)tid * 32 + k4 * 4);
            wcr[k4*4] = v.x; wcr[k4*4+1] = v.y; wcr[k4*4+2] = v.z; wcr[k4*4+3] = v.w;
        }
        const float cbr = cbv[tid];
        const float ap0v = act_pre0[b * 256 + tid];
        for (int t = 0; t < SP1; ++t) {
            float ap = fmaf((float)t, cbr, ap0v);
            const float4* ce = (const float4*)&cumE_l[t * 32];
#pragma unroll
            for (int k4 = 0; k4 < 8; k4++) {
                float4 e = ce[k4];
                ap = fmaf(e.x, wcr[k4*4], ap);   ap = fmaf(e.y, wcr[k4*4+1], ap);
                ap = fmaf(e.z, wcr[k4*4+2], ap); ap = fmaf(e.w, wcr[k4*4+3], ap);
            }
            rap_l[t * 260 + tid] = fmaxf(ap, 0.0f);
        }
    }
    __syncthreads();

    // ---- Phase B: fc2 partials ----
    {
        const int seg = tid >> 5, i = tid & 31;
        float wfc2r[32];
#pragma unroll
        for (int i4 = 0; i4 < 8; i4++) {
            float4 v = *(const float4*)(Wfc2 + (size_t)i * 256 + seg * 32 + i4 * 4);
            wfc2r[i4*4] = v.x; wfc2r[i4*4+1] = v.y; wfc2r[i4*4+2] = v.z; wfc2r[i4*4+3] = v.w;
        }
        for (int t = 0; t < SP1; ++t) {
            float part = 0.0f;
            const float4* rp = (const float4*)&rap_l[t * 260 + seg * 32];
#pragma unroll
            for (int i4 = 0; i4 < 8; i4++) {
                float4 rv = rp[i4];
                part = fmaf(rv.x, wfc2r[i4*4], part);   part = fmaf(rv.y, wfc2r[i4*4+1], part);
                part = fmaf(rv.z, wfc2r[i4*4+2], part); part = fmaf(rv.w, wfc2r[i4*4+3], part);
            }
            red_l[t * 256 + seg * 32 + i] = part;
        }
    }
    __syncthreads();

    // ---- Phase C: reduce -> x ----
    for (int p = 0; p < 5; p++) {
        int idx = p * 256 + tid;
        if (idx < SP1 * 32) {
            int t = idx >> 5, i = idx & 31;
            float x = bfc2[i];
#pragma unroll
            for (int s = 0; s < 8; s++) x += red_l[t * 256 + s * 32 + i];
            x_l[t * 32 + i] = x;
        }
    }
    __syncthreads();

    // ---- Phase D: gates pre-h -> xg (overlays rap) ----
    {
        const int g = tid & 127, half = tid >> 7;
        float wihr[32];
#pragma unroll
        for (int k4 = 0; k4 < 8; k4++) {
            float4 v = *(const float4*)(Wih + (size_t)g * 32 + k4 * 4);
            wihr[k4*4] = v.x; wihr[k4*4+1] = v.y; wihr[k4*4+2] = v.z; wihr[k4*4+3] = v.w;
        }
        const float bihg = bih[g] + bhh[g];
        for (int t = half; t < SP1; t += 2) {
            float gg = bihg;
            const float4* xp = (const float4*)&x_l[t * 32];
#pragma unroll
            for (int k4 = 0; k4 < 8; k4++) {
                float4 xv = xp[k4];
                gg = fmaf(xv.x, wihr[k4*4], gg);   gg = fmaf(xv.y, wihr[k4*4+1], gg);
                gg = fmaf(xv.z, wihr[k4*4+2], gg); gg = fmaf(xv.w, wihr[k4*4+3], gg);
            }
            xg_l[t * 128 + g] = gg;
        }
    }
    __syncthreads();

    // ---- LSTM chain (wave 0) || mask prep (threads 64..255) ----
    if (tid < 64) {
        float whh0[32], whh1[32];
#pragma unroll
        for (int k4 = 0; k4 < 8; k4++) {
            float4 v0 = *(const float4*)(Whh + (size_t)tid * 32 + k4 * 4);
            float4 v1 = *(const float4*)(Whh + (size_t)(tid + 64) * 32 + k4 * 4);
            whh0[k4*4] = v0.x; whh0[k4*4+1] = v0.y; whh0[k4*4+2] = v0.z; whh0[k4*4+3] = v0.w;
            whh1[k4*4] = v1.x; whh1[k4*4+1] = v1.y; whh1[k4*4+2] = v1.z; whh1[k4*4+3] = v1.w;
        }
        float c = 0.0f, h = 0.0f;
        for (int t = 0; t < SP1; ++t) {
            float g0 = xg_l[t * 128 + tid];
            float g1 = xg_l[t * 128 + 64 + tid];
            if (t > 0) {
#pragma unroll
                for (int k = 0; k < 32; k++) {
                    float hk = __shfl(h, k);
                    g0 = fmaf(hk, whh0[k], g0);
                    g1 = fmaf(hk, whh1[k], g1);
                }
            }
            float og0 = __shfl_xor(g0, 32);
            float og1 = __shfl_xor(g1, 32);
            float ig = fsig(g0);
            float fg = fsig(og0);
            float gv = ftanh(g1);
            float og = fsig(og1);
            float cn = fg * c + ig * gv;
            float hn = og * ftanh(cn);
            if (tid < 32) {
                c = cn; h = hn;
                h_all[t * 32 + tid] = hn;
            }
        }
    } else {
        for (int n = tid - 64; n < NP1; n += 192) {
            float m = (n < NN_) ? avail[(size_t)b * NN_ + n] : 1.0f;
            int tf = 1000;
#pragma unroll 8
            for (int s = 0; s < SS_; s++) {
                int sv = sel_l[s];
                if (sv == n) { m = 1.0f; if (s < tf) tf = s; }
            }
            m0_l[n] = m; tf_l[n] = tf;
        }
    }
    __syncthreads();

    // ---- logits via bf16 MFMA ----
    {
        s16x8 afr[3];
#pragma unroll
        for (int mt = 0; mt < 3; mt++) {
            int row = mt * 16 + nl;
            s16x8 av;
#pragma unroll
            for (int jj = 0; jj < 8; jj++) {
                float v = (row < SP1) ? h_all[row * 32 + q * 8 + jj] : 0.0f;
                av[jj] = f2bf(v);
            }
            afr[mt] = av;
        }
        for (int tt = w; tt < 33; tt += 4) {
            int n = tt * 16 + nl;
            bool nv = n < NP1;
            s16x8 bv = nv ? *(const s16x8*)(pkbf + ((size_t)b * NP1 + n) * 32 + q * 8) : (s16x8)0;
            f32x4 acc[3];
#pragma unroll
            for (int mt = 0; mt < 3; mt++)
                acc[mt] = __builtin_amdgcn_mfma_f32_16x16x32_bf16(afr[mt], bv, (f32x4)0.0f, 0, 0, 0);
            float m0v = nv ? m0_l[n] : 0.0f;
            int tfv = nv ? tf_l[n] : 0;
#pragma unroll
            for (int mt = 0; mt < 3; mt++)
#pragma unroll
                for (int r = 0; r < 4; r++) {
                    int t = mt * 16 + q * 4 + r;
                    if (t < SP1 && nv) {
                        float mv = (t <= tfv) ? m0v : 0.0f;
                        logits[((size_t)b * SP1 + t) * NP1 + n] = acc[mt][r] - (1.0f - mv) * 1e9f;
                    }
                }
        }
    }

    // ---- emb_out ----
#pragma unroll
    for (int p = 0; p < 4; p++) {
        int i = p * 256 + tid;
        float acc = emb0[(size_t)b * D_IN + i] + 32.0f * bemb[i];
        const float* wr = Wemb + (size_t)i * 32;
#pragma unroll
        for (int k4 = 0; k4 < 8; k4++) {
            float4 wv = *(const float4*)(wr + k4 * 4);
            acc = fmaf(ssel_l[k4*4+0], wv.x, acc);
            acc = fmaf(ssel_l[k4*4+1], wv.y, acc);
            acc = fmaf(ssel_l[k4*4+2], wv.z, acc);
            acc = fmaf(ssel_l[k4*4+3], wv.w, acc);
        }
        emb_out[(size_t)b * D_IN + i] = acc;
    }
}

extern "C" void kernel_launch(void* const* d_in, const int* in_sizes, int n_in,
                              void* d_out, int out_size, void* d_ws, size_t ws_size,
                              hipStream_t stream)
{
    (void)in_sizes; (void)n_in; (void)out_size; (void)ws_size;
    const float* embedding = (const float*)d_in[0];
    const float* atm       = (const float*)d_in[1];
    const float* avail     = (const float*)d_in[2];
    const float* ent       = (const float*)d_in[3];
    const int*   sel       = (const int*)  d_in[4];
    const float* endv      = (const float*)d_in[5];
    const float* Wk   = (const float*)d_in[6];
    const float* bk   = (const float*)d_in[7];
    const float* Wf   = (const float*)d_in[8];
    const float* bf   = (const float*)d_in[9];
    const float* Wfc1 = (const float*)d_in[10];
    const float* bfc1 = (const float*)d_in[11];
    const float* Wfc2 = (const float*)d_in[12];
    const float* bfc2 = (const float*)d_in[13];
    const float* Wemb = (const float*)d_in[14];
    const float* bemb = (const float*)d_in[15];
    const float* Wih  = (const float*)d_in[16];
    const float* bih  = (const float*)d_in[17];
    const float* Whh  = (const float*)d_in[18];
    const float* bhh  = (const float*)d_in[19];

    float* ws = (float*)d_ws;
    float* act_pre = ws;                          // 65536 f
    float* WcombT  = act_pre + BB_ * 256;         // 8192 f
    float* cbv     = WcombT + 256 * 32;           // 256 f
    short* pkbf    = (short*)(cbv + 256);         // 256*513*32 shorts

    float* logits  = (float*)d_out;
    float* emb_out = logits + (size_t)BB_ * SP1 * NP1;

    front_kernel<<<1283, 256, 0, stream>>>(ent, Wk, bk, endv, Wemb, bemb,
                                           Wfc1, embedding, bfc1, atm, Wf, bf,
                                           pkbf, WcombT, cbv, act_pre);
    back_kernel<<<BB_, 256, 0, stream>>>(pkbf, act_pre, sel, avail,
                                         Wfc2, bfc2, Wih, bih, bhh, Whh,
                                         WcombT, cbv, embedding, Wemb, bemb,
                                         logits, emb_out);
}